// Round 6
// baseline (967.656 us; speedup 1.0000x reference)
//
#include <hip/hip_runtime.h>

typedef __bf16 bf16x8 __attribute__((ext_vector_type(8)));
typedef float f32x4 __attribute__((ext_vector_type(4)));
typedef unsigned short ushortT;

__device__ __forceinline__ unsigned short f2bf(float f) {
    unsigned u = __float_as_uint(f);
    u += 0x7fffu + ((u >> 16) & 1u);
    return (unsigned short)(u >> 16);
}
__device__ __forceinline__ float bf2f(unsigned short h) {
    return __uint_as_float((unsigned)h << 16);
}

// ---------------- merged weight prep (one launch for all 9 weight tensors) ----------------
// conv wpreps: f32 [3][Co][Ci][27] -> bf16 [(i*27+tap)][Co][Ci]  (out-index = flat idx)
// conv1 wprep: f32 (7,64,1,7,7,7) -> bf16 [co][3136], k=(kt*7+kd)*64+kh*8+kw (kh/kw pad 8)
__global__ void wprep_all(const float* __restrict__ c1w,
                          const float* __restrict__ w11, const float* __restrict__ w12,
                          const float* __restrict__ w21, const float* __restrict__ w22,
                          const float* __restrict__ w31, const float* __restrict__ w32,
                          const float* __restrict__ w41, const float* __restrict__ w42,
                          ushortT* __restrict__ o1,
                          ushortT* __restrict__ o11, ushortT* __restrict__ o12,
                          ushortT* __restrict__ o21, ushortT* __restrict__ o22,
                          ushortT* __restrict__ o31, ushortT* __restrict__ o32,
                          ushortT* __restrict__ o41, ushortT* __restrict__ o42,
                          ushortT* __restrict__ zb) {
    if (blockIdx.x == 0 && threadIdx.x < 128) zb[threadIdx.x] = 0;
    long stride = (long)gridDim.x * 256;
    for (long idx = (long)blockIdx.x * 256 + threadIdx.x; idx < 42668032L; idx += stride) {
        const float* in; ushortT* out; int Ci, Co; long local;
        if (idx < 2654208L) {
            if (idx < 663552L) {
                if (idx < 331776L) { in = w11; out = o11; Ci = 64; Co = 64; local = idx; }
                else               { in = w12; out = o12; Ci = 64; Co = 64; local = idx - 331776L; }
            } else if (idx < 1327104L) { in = w21; out = o21; Ci = 64;  Co = 128; local = idx - 663552L; }
            else                       { in = w22; out = o22; Ci = 128; Co = 128; local = idx - 1327104L; }
        } else if (idx < 10616832L) {
            if (idx < 5308416L) { in = w31; out = o31; Ci = 128; Co = 256; local = idx - 2654208L; }
            else                { in = w32; out = o32; Ci = 256; Co = 256; local = idx - 5308416L; }
        } else if (idx < 42467328L) {
            if (idx < 21233664L) { in = w41; out = o41; Ci = 256; Co = 512; local = idx - 10616832L; }
            else                 { in = w42; out = o42; Ci = 512; Co = 512; local = idx - 21233664L; }
        } else {
            // conv1 weights
            int e = (int)(idx - 42467328L);
            int k = e % 3136, co = e / 3136;
            int kw = k & 7, kh = (k >> 3) & 7, kdt = k >> 6;
            int kt = kdt / 7, kd = kdt % 7;
            float v = 0.f;
            if (kh < 7 && kw < 7)
                v = c1w[(size_t)(kt * 64 + co) * 343 + kd * 49 + kh * 7 + kw];
            o1[e] = f2bf(v);
            continue;
        }
        int ci = (int)(local % Ci); long t = local / Ci;
        int co = (int)(t % Co); t /= Co;
        int tap = (int)(t % 27); int i = (int)(t / 27);
        out[local] = f2bf(in[((size_t)(i * Co + co) * Ci + ci) * 27 + tap]);
    }
}

// ---------------- conv1 v4: v2 MFMA structure, stride-18 LDS rows, bf16 [pos][64] out ------
// block = 64 pos (tile 1x4x4x4), 4 waves = 4 co-blocks of 16. wave: 16co x 64pos (m=4).
// LDS x tile [lt7][ld13][lh14][lw 18(pad of 14)] bf16: row stride 9 dwords (odd) -> <=2-way
// bank aliasing (free). A (weights) from global, 1 load per 4 MFMA.
__global__ __launch_bounds__(256) void conv1_mfma4(const float* __restrict__ x,
                                                   const ushortT* __restrict__ aw,
                                                   ushortT* __restrict__ out) {
    __shared__ ushortT xs[22932]; // 45,864 B -> 3 blocks/CU

    int bid = blockIdx.x;
    int wt = bid % 5; int r = bid / 5;
    int ht = r % 5; r /= 5;
    int dt = r % 5; int ot = r / 5; // grid 5*5*5*18 = 2250
    int ow0 = wt * 4, oh0 = ht * 4, od0 = dt * 4;
    int it0 = 2 * ot - 3, id0 = 2 * od0 - 3, ih0 = 2 * oh0 - 3, iw0 = 2 * ow0 - 3;

    int tid = threadIdx.x;
    // ---- stage x tile: rows = (lt*13+ld)*14+lh (1274), 14 w used, stride 18 ----
    for (int e = tid; e < 8918; e += 256) {
        int c2 = e % 7;        // lw = 2*c2 .. 2*c2+1
        int row = e / 7;
        int lh = row % 14; int r2 = row / 14;
        int ld = r2 % 13; int lt = r2 / 13;
        int gt = it0 + lt, gd = id0 + ld, gh = ih0 + lh;
        int gw0 = iw0 + 2 * c2, gw1 = gw0 + 1;
        bool rowok = ((unsigned)gt < 36u) && ((unsigned)gd < 36u) && ((unsigned)gh < 36u);
        const float* xr = x + (((long)gt * 36 + gd) * 36 + gh) * 36;
        float f0 = (rowok && (unsigned)gw0 < 36u) ? xr[gw0] : 0.f;
        float f1 = (rowok && (unsigned)gw1 < 36u) ? xr[gw1] : 0.f;
        *(unsigned*)(xs + row * 18 + 2 * c2) = (unsigned)f2bf(f0) | ((unsigned)f2bf(f1) << 16);
    }
    __syncthreads();

    int lane = tid & 63, wv = tid >> 6;
    int l15 = lane & 15, g = lane >> 4;
    int dh = l15 >> 2, dw = l15 & 3;

    const ushortT* ap = aw + (size_t)(wv * 16 + l15) * 3136 + g * 8;
    int laneoff = (2 * dh + g) * 18 + 2 * dw;

    f32x4 acc[4];
#pragma unroll
    for (int m = 0; m < 4; ++m) acc[m] = (f32x4){0.f, 0.f, 0.f, 0.f};

    int ka = 0;
    for (int kt = 0; kt < 7; ++kt) {
        for (int kd = 0; kd < 7; ++kd) {
            int rb = kt * 3276 + kd * 252 + laneoff;
#pragma unroll
            for (int khq = 0; khq < 2; ++khq) {
                bf16x8 av = *(const bf16x8*)(ap + ka); ka += 32;
                int fb = rb + khq * 72;
#pragma unroll
                for (int m = 0; m < 4; ++m) {
                    int off = fb + m * 504;
                    union { unsigned u[4]; bf16x8 v; } bb;
                    bb.u[0] = *(const unsigned*)(xs + off);
                    bb.u[1] = *(const unsigned*)(xs + off + 2);
                    bb.u[2] = *(const unsigned*)(xs + off + 4);
                    bb.u[3] = *(const unsigned*)(xs + off + 6);
                    acc[m] = __builtin_amdgcn_mfma_f32_16x16x32_bf16(av, bb.v, acc[m], 0, 0, 0);
                }
            }
        }
    }

    // C: col=l15 -> pos(dh,dw); row = g*4+reg -> co = wv*16 + g*4 + reg
    int oh = oh0 + dh, ow = ow0 + dw;
    if (oh < 18 && ow < 18) {
#pragma unroll
        for (int m = 0; m < 4; ++m) {
            int od = od0 + m;
            if (od < 18) {
                int pos = ((ot * 18 + od) * 18 + oh) * 18 + ow;
                ushort4 st;
                st.x = f2bf(fmaxf(acc[m][0], 0.f));
                st.y = f2bf(fmaxf(acc[m][1], 0.f));
                st.z = f2bf(fmaxf(acc[m][2], 0.f));
                st.w = f2bf(fmaxf(acc[m][3], 0.f));
                *(ushort4*)(out + (size_t)pos * 64 + wv * 16 + g * 4) = st;
            }
        }
    }
}

// ---------------- maxpool 3^4 s2 p1: bf16 [18^4][64] -> bf16 [9^4][64]; zero-fills zb ------
__global__ void maxpool2(const ushortT* __restrict__ in, ushortT* __restrict__ out,
                         ushortT* __restrict__ zb) {
    int idx = blockIdx.x * 256 + threadIdx.x;
    if (idx < 128) zb[idx] = 0;
    if (idx >= 6561 * 16) return;
    int c4 = idx & 15;
    int p = idx >> 4;
    int ow = p % 9; int t = p / 9;
    int oh = t % 9; t /= 9;
    int od = t % 9; int ot = t / 9;
    ushort4 m = {0, 0, 0, 0};
    for (int kt = 0; kt < 3; ++kt) { int it = 2 * ot + kt - 1; if ((unsigned)it >= 18u) continue;
        for (int kd = 0; kd < 3; ++kd) { int id = 2 * od + kd - 1; if ((unsigned)id >= 18u) continue;
            for (int kh = 0; kh < 3; ++kh) { int ih = 2 * oh + kh - 1; if ((unsigned)ih >= 18u) continue;
                int rb = ((it * 18 + id) * 18 + ih) * 18;
                for (int kw = 0; kw < 3; ++kw) { int iw = 2 * ow + kw - 1; if ((unsigned)iw >= 18u) continue;
                    ushort4 v = *(const ushort4*)(in + (size_t)(rb + iw) * 64 + c4 * 4);
                    m.x = v.x > m.x ? v.x : m.x;
                    m.y = v.y > m.y ? v.y : m.y;
                    m.z = v.z > m.z ? v.z : m.z;
                    m.w = v.w > m.w ? v.w : m.w;
                }
            }
        }
    }
    *(ushort4*)(out + (size_t)p * 64 + c4 * 4) = m;
}

// ---------------- MFMA implicit-GEMM residual conv (+ optional merged 1x1 downsample) ------
template <int KC, int FUSE>
__global__ void convmfma(const ushortT* __restrict__ xb, const ushortT* __restrict__ wt,
                         const float* __restrict__ bias, const ushortT* __restrict__ res,
                         ushortT* __restrict__ outb, float* __restrict__ part,
                         const ushortT* __restrict__ zq,
                         int Ci, int Co, int T, int O, int stride, int chunk,
                         const float* __restrict__ dwW, ushortT* __restrict__ dwOut) {
    // merged downsample branch: extra blockIdx.y row does the 1x1 stride-2 conv
    if (dwW && blockIdx.y == (unsigned)(Co >> 6)) {
        int O2 = O * O, O3 = O2 * O, O4 = O3 * O;
        int total = Co * O4;
        int sthr = gridDim.x * gridDim.z * 256;
        for (int idx = (blockIdx.z * gridDim.x + blockIdx.x) * 256 + threadIdx.x;
             idx < total; idx += sthr) {
            int co = idx % Co;
            int pos = idx / Co;
            int ow = pos % O, oh = (pos / O) % O, od = (pos / O2) % O, ot = pos / O3;
            int ip = (((2 * ot) * T + 2 * od) * T + 2 * oh) * T + 2 * ow;
            const ushortT* xp = xb + (size_t)ip * Ci;
            const float* wp = dwW + (size_t)co * Ci;
            float acc = 0.f;
            for (int c8 = 0; c8 < Ci; c8 += 8) {
                uint4 xv = *(const uint4*)(xp + c8);
                float4 w0 = *(const float4*)(wp + c8);
                float4 w1 = *(const float4*)(wp + c8 + 4);
                acc = fmaf(bf2f((unsigned short)(xv.x & 0xffff)), w0.x, acc);
                acc = fmaf(bf2f((unsigned short)(xv.x >> 16)),    w0.y, acc);
                acc = fmaf(bf2f((unsigned short)(xv.y & 0xffff)), w0.z, acc);
                acc = fmaf(bf2f((unsigned short)(xv.y >> 16)),    w0.w, acc);
                acc = fmaf(bf2f((unsigned short)(xv.z & 0xffff)), w1.x, acc);
                acc = fmaf(bf2f((unsigned short)(xv.z >> 16)),    w1.y, acc);
                acc = fmaf(bf2f((unsigned short)(xv.w & 0xffff)), w1.z, acc);
                acc = fmaf(bf2f((unsigned short)(xv.w >> 16)),    w1.w, acc);
            }
            dwOut[idx] = f2bf(acc);
        }
        return;
    }

    int lane = threadIdx.x & 63;
    int wv = threadIdx.x >> 6;
    int p0 = blockIdx.x * 16;
    int co0 = (blockIdx.y * 4 + wv) * 16;
    int cbase = blockIdx.z * chunk;

    int pn = p0 + (lane & 15);
    int O2 = O * O, O3 = O2 * O, O4 = O3 * O;
    bool pv = pn < O4;
    int pc = pv ? pn : 0;
    int ow = pc % O, oh = (pc / O) % O, od = (pc / O2) % O, ot = pc / O3;
    int g = lane >> 4;
    int kl = cbase + g * 8;

    const ushortT* aRow = wt + (size_t)(co0 + (lane & 15)) * Ci + kl;
    size_t tapStride = (size_t)Co * Ci;
    const ushortT* zp = zq + g * 8;

    f32x4 acc = {0.f, 0.f, 0.f, 0.f};

    int itb = ot * stride - 1, idb = od * stride - 1, ihb = oh * stride - 1, iwb = ow * stride - 1;

    for (int i = 0; i < 3; ++i) {
        int it = itb + i;
        bool vt = pv && ((unsigned)it < (unsigned)T);
        for (int kd = 0; kd < 3; ++kd) {
            int id = idb + kd;
            bool vdd = vt && ((unsigned)id < (unsigned)T);
            int btd = (it * T + id) * T;
            for (int kh = 0; kh < 3; ++kh) {
                int ih = ihb + kh;
                bool vh = vdd && ((unsigned)ih < (unsigned)T);
                for (int kw = 0; kw < 3; ++kw) {
                    int iw = iwb + kw;
                    bool v = vh && ((unsigned)iw < (unsigned)T);
                    int ip = (btd + ih) * T + iw;
                    const ushortT* bp = v ? (xb + (size_t)ip * Ci + kl) : zp;
                    int tapIdx = (i * 9 + kd * 3 + kh) * 3 + kw;
                    const ushortT* apw = aRow + (size_t)tapIdx * tapStride;
#pragma unroll
                    for (int kc = 0; kc < KC; ++kc) {
                        bf16x8 av = *(const bf16x8*)(apw + kc * 32);
                        bf16x8 bv = *(const bf16x8*)(bp + kc * 32);
                        acc = __builtin_amdgcn_mfma_f32_16x16x32_bf16(av, bv, acc, 0, 0, 0);
                    }
                }
            }
        }
    }

    if (!pv) return;
    int cob = co0 + g * 4;
    if (FUSE) {
        float bb[4] = {0.f, 0.f, 0.f, 0.f};
        for (int i = 0; i < 3; ++i) {
            int it = itb + i;
            if ((unsigned)it < (unsigned)T) {
#pragma unroll
                for (int r = 0; r < 4; ++r) bb[r] += bias[i * Co + cob + r];
            }
        }
        float rv[4] = {0.f, 0.f, 0.f, 0.f};
        if (res) {
            ushort4 rr = *(const ushort4*)(res + (size_t)pn * Co + cob);
            rv[0] = bf2f(rr.x); rv[1] = bf2f(rr.y); rv[2] = bf2f(rr.z); rv[3] = bf2f(rr.w);
        }
        ushort4 st;
        st.x = f2bf(fmaxf(acc[0] + bb[0] + rv[0], 0.f));
        st.y = f2bf(fmaxf(acc[1] + bb[1] + rv[1], 0.f));
        st.z = f2bf(fmaxf(acc[2] + bb[2] + rv[2], 0.f));
        st.w = f2bf(fmaxf(acc[3] + bb[3] + rv[3], 0.f));
        *(ushort4*)(outb + (size_t)pn * Co + cob) = st;
    } else {
        *(f32x4*)(part + ((size_t)blockIdx.z * O4 + pn) * Co + cob) = acc;
    }
}

// ---------------- finalize for k-split convs ----------------
__global__ void finalize_k(const float* __restrict__ part, int KS,
                           const float* __restrict__ bias, const ushortT* __restrict__ res,
                           ushortT* __restrict__ outb, int Co, int O4, int T, int O, int stride,
                           int total) {
    int idx = blockIdx.x * 256 + threadIdx.x;
    if (idx >= total) return;
    int co = idx % Co;
    int pos = idx / Co;
    float v = 0.f;
    for (int z = 0; z < KS; ++z) v += part[((size_t)z * O4 + pos) * Co + co];
    int ot = pos / (O * O * O);
    for (int i = 0; i < 3; ++i) {
        int it = ot * stride + i - 1;
        if ((unsigned)it < (unsigned)T) v += bias[i * Co + co];
    }
    if (res) v += bf2f(res[idx]);
    outb[idx] = f2bf(fmaxf(v, 0.f));
}

// ---------------- avgpool 2^4 + FC (512 -> 1) ----------------
__global__ void avgfc2(const ushortT* __restrict__ xin, const float* __restrict__ fw,
                       const float* __restrict__ fb, float* __restrict__ out) {
    __shared__ float ls[8];
    int t = threadIdx.x; // 512
    float s = 0.f;
#pragma unroll
    for (int pp = 0; pp < 16; ++pp) s += bf2f(xin[pp * 512 + t]);
    s = s * (1.f / 16.f) * fw[t];
    for (int off = 32; off > 0; off >>= 1) s += __shfl_xor(s, off, 64);
    if ((t & 63) == 0) ls[t >> 6] = s;
    __syncthreads();
    if (t == 0) {
        float tot = 0.f;
#pragma unroll
        for (int i = 0; i < 8; ++i) tot += ls[i];
        out[0] = tot + fb[0];
    }
}

extern "C" void kernel_launch(void* const* d_in, const int* in_sizes, int n_in,
                              void* d_out, int out_size, void* d_ws, size_t ws_size,
                              hipStream_t stream) {
    const float* x       = (const float*)d_in[0];
    const float* conv1_w = (const float*)d_in[1];
    const float* l1_w1 = (const float*)d_in[2];
    const float* l1_b1 = (const float*)d_in[3];
    const float* l1_w2 = (const float*)d_in[4];
    const float* l1_b2 = (const float*)d_in[5];
    const float* l2_w1 = (const float*)d_in[6];
    const float* l2_b1 = (const float*)d_in[7];
    const float* l2_w2 = (const float*)d_in[8];
    const float* l2_b2 = (const float*)d_in[9];
    const float* l2_dw = (const float*)d_in[10];
    const float* l3_w1 = (const float*)d_in[11];
    const float* l3_b1 = (const float*)d_in[12];
    const float* l3_w2 = (const float*)d_in[13];
    const float* l3_b2 = (const float*)d_in[14];
    const float* l3_dw = (const float*)d_in[15];
    const float* l4_w1 = (const float*)d_in[16];
    const float* l4_b1 = (const float*)d_in[17];
    const float* l4_w2 = (const float*)d_in[18];
    const float* l4_b2 = (const float*)d_in[19];
    const float* l4_dw = (const float*)d_in[20];
    const float* fc_w  = (const float*)d_in[21];
    const float* fc_b  = (const float*)d_in[22];
    float* outp = (float*)d_out;

    char* bp = (char*)d_ws;
    auto alloc = [&](size_t bytes) {
        char* r = bp;
        bp += (bytes + 255) & ~(size_t)255;
        return (void*)r;
    };
    ushortT* A16 = (ushortT*)alloc(6718464ull * 2); // conv1 out bf16 [18^4][64]
    ushortT* Aw1 = (ushortT*)alloc(200704ull * 2);
    ushortT* X0 = (ushortT*)alloc(419904ull * 2);
    ushortT* Y1 = (ushortT*)alloc(419904ull * 2);
    ushortT* X1 = (ushortT*)alloc(419904ull * 2);
    ushortT* Y2 = (ushortT*)alloc(80000ull * 2);
    ushortT* R2 = (ushortT*)alloc(80000ull * 2);
    ushortT* X2 = (ushortT*)alloc(80000ull * 2);
    ushortT* Y3 = (ushortT*)alloc(20736ull * 2);
    ushortT* R3 = (ushortT*)alloc(20736ull * 2);
    ushortT* X3 = (ushortT*)alloc(20736ull * 2);
    ushortT* Y4 = (ushortT*)alloc(8192ull * 2);
    ushortT* R4 = (ushortT*)alloc(8192ull * 2);
    ushortT* X4 = (ushortT*)alloc(8192ull * 2);
    ushortT* W11 = (ushortT*)alloc(331776ull * 2);
    ushortT* W12 = (ushortT*)alloc(331776ull * 2);
    ushortT* W21 = (ushortT*)alloc(663552ull * 2);
    ushortT* W22 = (ushortT*)alloc(1327104ull * 2);
    ushortT* W31 = (ushortT*)alloc(2654208ull * 2);
    ushortT* W32 = (ushortT*)alloc(5308416ull * 2);
    ushortT* W41 = (ushortT*)alloc(10616832ull * 2);
    ushortT* W42 = (ushortT*)alloc(21233664ull * 2);
    float* P    = (float*)alloc(165888ull * 4);
    ushortT* ZB = (ushortT*)alloc(256);
    if ((size_t)(bp - (char*)d_ws) > ws_size) return; // workspace too small: fail cleanly

    // ---- all weight prep in one launch ----
    wprep_all<<<8192, 256, 0, stream>>>(conv1_w, l1_w1, l1_w2, l2_w1, l2_w2, l3_w1, l3_w2,
                                        l4_w1, l4_w2,
                                        Aw1, W11, W12, W21, W22, W31, W32, W41, W42, ZB);

    // ---- stem ----
    conv1_mfma4<<<2250, 256, 0, stream>>>(x, Aw1, A16);
    maxpool2<<<411, 256, 0, stream>>>(A16, X0, ZB);

    // ---- layer1: 64->64, T=9, s1, identity residual ----
    convmfma<2, 1><<<dim3(411, 1, 1), 256, 0, stream>>>(X0, W11, l1_b1, nullptr, Y1, nullptr,
                                                        ZB, 64, 64, 9, 9, 1, 64,
                                                        nullptr, nullptr);
    convmfma<2, 1><<<dim3(411, 1, 1), 256, 0, stream>>>(Y1, W12, l1_b2, X0, X1, nullptr,
                                                        ZB, 64, 64, 9, 9, 1, 64,
                                                        nullptr, nullptr);

    // ---- layer2: 64->128, 9->5, s2 (dw merged into c1 launch) ----
    convmfma<2, 1><<<dim3(40, 3, 1), 256, 0, stream>>>(X1, W21, l2_b1, nullptr, Y2, nullptr,
                                                       ZB, 64, 128, 9, 5, 2, 64,
                                                       l2_dw, R2);
    convmfma<4, 1><<<dim3(40, 2, 1), 256, 0, stream>>>(Y2, W22, l2_b2, R2, X2, nullptr,
                                                       ZB, 128, 128, 5, 5, 1, 128,
                                                       nullptr, nullptr);

    // ---- layer3: 128->256, 5->3, s2 (c1 KS=4 + merged dw; c2 KS=8) ----
    convmfma<1, 0><<<dim3(6, 5, 4), 256, 0, stream>>>(X2, W31, nullptr, nullptr, nullptr, P,
                                                      ZB, 128, 256, 5, 3, 2, 32,
                                                      l3_dw, R3);
    finalize_k<<<81, 256, 0, stream>>>(P, 4, l3_b1, nullptr, Y3, 256, 81, 5, 3, 2, 20736);
    convmfma<1, 0><<<dim3(6, 4, 8), 256, 0, stream>>>(Y3, W32, nullptr, nullptr, nullptr, P,
                                                      ZB, 256, 256, 3, 3, 1, 32,
                                                      nullptr, nullptr);
    finalize_k<<<81, 256, 0, stream>>>(P, 8, l3_b2, R3, X3, 256, 81, 3, 3, 1, 20736);

    // ---- layer4: 256->512, 3->2, s2 (c1 KS=8 + merged dw; c2 KS=16) ----
    convmfma<1, 0><<<dim3(1, 9, 8), 256, 0, stream>>>(X3, W41, nullptr, nullptr, nullptr, P,
                                                      ZB, 256, 512, 3, 2, 2, 32,
                                                      l4_dw, R4);
    finalize_k<<<32, 256, 0, stream>>>(P, 8, l4_b1, nullptr, Y4, 512, 16, 3, 2, 2, 8192);
    convmfma<1, 0><<<dim3(1, 8, 16), 256, 0, stream>>>(Y4, W42, nullptr, nullptr, nullptr, P,
                                                       ZB, 512, 512, 2, 2, 1, 32,
                                                       nullptr, nullptr);
    finalize_k<<<32, 256, 0, stream>>>(P, 16, l4_b2, R4, X4, 512, 16, 2, 2, 1, 8192);

    // ---- head ----
    avgfc2<<<1, 512, 0, stream>>>(X4, fc_w, fc_b, outp);
}

// Round 7
// 633.618 us; speedup vs baseline: 1.5272x; 1.5272x over previous
//
#include <hip/hip_runtime.h>

typedef __bf16 bf16x8 __attribute__((ext_vector_type(8)));
typedef float f32x4 __attribute__((ext_vector_type(4)));
typedef unsigned short ushortT;

__device__ __forceinline__ unsigned short f2bf(float f) {
    unsigned u = __float_as_uint(f);
    u += 0x7fffu + ((u >> 16) & 1u);
    return (unsigned short)(u >> 16);
}
__device__ __forceinline__ float bf2f(unsigned short h) {
    return __uint_as_float((unsigned)h << 16);
}

// ---------------- combined weight prep, both-sides coalesced ----------------
// Blocks [0, 5760): one block per (tensor, i, co): f32 [Ci][27] -> bf16 rows [tap][Ci]
//   (LDS transpose: contiguous float4 reads, contiguous ushort4 writes).
// Blocks [5760, 6544): conv1 repack (7,64,1,7,7,7) f32 -> bf16 [co][3136],
//   k=(kt*7+kd)*64+kh*8+kw (kh/kw padded to 8, pad slots 0).
__global__ __launch_bounds__(256) void wprep_combined(
        const float* __restrict__ c1w,
        const float* __restrict__ w11, const float* __restrict__ w12,
        const float* __restrict__ w21, const float* __restrict__ w22,
        const float* __restrict__ w31, const float* __restrict__ w32,
        const float* __restrict__ w41, const float* __restrict__ w42,
        ushortT* __restrict__ o1,
        ushortT* __restrict__ o11, ushortT* __restrict__ o12,
        ushortT* __restrict__ o21, ushortT* __restrict__ o22,
        ushortT* __restrict__ o31, ushortT* __restrict__ o32,
        ushortT* __restrict__ o41, ushortT* __restrict__ o42,
        ushortT* __restrict__ zb) {
    __shared__ float tile[13824]; // up to Ci=512: 512*27 floats
    int b = blockIdx.x;
    int tid = threadIdx.x;

    if (b >= 5760) {
        if (b == 5760 && tid < 128) zb[tid] = 0;
        int e = (b - 5760) * 256 + tid; // < 200704
        if (e < 200704) {
            int k = e % 3136, co = e / 3136;
            int kw = k & 7, kh = (k >> 3) & 7, kdt = k >> 6;
            int kt = kdt / 7, kd = kdt % 7;
            float v = 0.f;
            if (kh < 7 && kw < 7)
                v = c1w[(size_t)(kt * 64 + co) * 343 + kd * 49 + kh * 7 + kw];
            o1[e] = f2bf(v);
        }
        return;
    }

    const float* in; ushortT* out; int Ci, Co, lb;
    if (b < 1152) {
        if (b < 384) {
            if (b < 192) { in = w11; out = o11; Ci = 64; Co = 64; lb = b; }
            else         { in = w12; out = o12; Ci = 64; Co = 64; lb = b - 192; }
        } else if (b < 768) { in = w21; out = o21; Ci = 64;  Co = 128; lb = b - 384; }
        else                { in = w22; out = o22; Ci = 128; Co = 128; lb = b - 768; }
    } else if (b < 2688) {
        if (b < 1920) { in = w31; out = o31; Ci = 128; Co = 256; lb = b - 1152; }
        else          { in = w32; out = o32; Ci = 256; Co = 256; lb = b - 1920; }
    } else {
        if (b < 4224) { in = w41; out = o41; Ci = 256; Co = 512; lb = b - 2688; }
        else          { in = w42; out = o42; Ci = 512; Co = 512; lb = b - 4224; }
    }
    int i = lb / Co, co = lb % Co;
    const float* src = in + (size_t)(i * Co + co) * Ci * 27;
    int n4 = (Ci * 27) >> 2;
    for (int e = tid; e < n4; e += 256)
        *(float4*)(tile + e * 4) = *(const float4*)(src + e * 4);
    __syncthreads();
    int qn = Ci >> 2;
    int wn = 27 * qn;
    ushortT* obase = out + (size_t)(i * 27) * Co * Ci + (size_t)co * Ci;
    size_t tapstride = (size_t)Co * Ci;
    for (int e = tid; e < wn; e += 256) {
        int tap = e / qn, q = e - tap * qn;
        ushort4 v;
        v.x = f2bf(tile[(4 * q + 0) * 27 + tap]);
        v.y = f2bf(tile[(4 * q + 1) * 27 + tap]);
        v.z = f2bf(tile[(4 * q + 2) * 27 + tap]);
        v.w = f2bf(tile[(4 * q + 3) * 27 + tap]);
        *(ushort4*)(obase + tap * tapstride + 4 * q) = v;
    }
}

// ---------------- conv1 v4: MFMA implicit im2col, stride-18 LDS rows, bf16 [pos][64] out ---
// block = 64 pos (tile 1x4x4x4), 4 waves = 4 co-blocks of 16. wave: 16co x 64pos (m=4).
__global__ __launch_bounds__(256) void conv1_mfma4(const float* __restrict__ x,
                                                   const ushortT* __restrict__ aw,
                                                   ushortT* __restrict__ out) {
    __shared__ ushortT xs[22932]; // 45,864 B -> 3 blocks/CU

    int bid = blockIdx.x;
    int wt = bid % 5; int r = bid / 5;
    int ht = r % 5; r /= 5;
    int dt = r % 5; int ot = r / 5; // grid 5*5*5*18 = 2250
    int ow0 = wt * 4, oh0 = ht * 4, od0 = dt * 4;
    int it0 = 2 * ot - 3, id0 = 2 * od0 - 3, ih0 = 2 * oh0 - 3, iw0 = 2 * ow0 - 3;

    int tid = threadIdx.x;
    for (int e = tid; e < 8918; e += 256) {
        int c2 = e % 7;
        int row = e / 7;
        int lh = row % 14; int r2 = row / 14;
        int ld = r2 % 13; int lt = r2 / 13;
        int gt = it0 + lt, gd = id0 + ld, gh = ih0 + lh;
        int gw0 = iw0 + 2 * c2, gw1 = gw0 + 1;
        bool rowok = ((unsigned)gt < 36u) && ((unsigned)gd < 36u) && ((unsigned)gh < 36u);
        const float* xr = x + (((long)gt * 36 + gd) * 36 + gh) * 36;
        float f0 = (rowok && (unsigned)gw0 < 36u) ? xr[gw0] : 0.f;
        float f1 = (rowok && (unsigned)gw1 < 36u) ? xr[gw1] : 0.f;
        *(unsigned*)(xs + row * 18 + 2 * c2) = (unsigned)f2bf(f0) | ((unsigned)f2bf(f1) << 16);
    }
    __syncthreads();

    int lane = tid & 63, wv = tid >> 6;
    int l15 = lane & 15, g = lane >> 4;
    int dh = l15 >> 2, dw = l15 & 3;

    const ushortT* ap = aw + (size_t)(wv * 16 + l15) * 3136 + g * 8;
    int laneoff = (2 * dh + g) * 18 + 2 * dw;

    f32x4 acc[4];
#pragma unroll
    for (int m = 0; m < 4; ++m) acc[m] = (f32x4){0.f, 0.f, 0.f, 0.f};

    int ka = 0;
    for (int kt = 0; kt < 7; ++kt) {
        for (int kd = 0; kd < 7; ++kd) {
            int rb = kt * 3276 + kd * 252 + laneoff;
#pragma unroll
            for (int khq = 0; khq < 2; ++khq) {
                bf16x8 av = *(const bf16x8*)(ap + ka); ka += 32;
                int fb = rb + khq * 72;
#pragma unroll
                for (int m = 0; m < 4; ++m) {
                    int off = fb + m * 504;
                    union { unsigned u[4]; bf16x8 v; } bb;
                    bb.u[0] = *(const unsigned*)(xs + off);
                    bb.u[1] = *(const unsigned*)(xs + off + 2);
                    bb.u[2] = *(const unsigned*)(xs + off + 4);
                    bb.u[3] = *(const unsigned*)(xs + off + 6);
                    acc[m] = __builtin_amdgcn_mfma_f32_16x16x32_bf16(av, bb.v, acc[m], 0, 0, 0);
                }
            }
        }
    }

    int oh = oh0 + dh, ow = ow0 + dw;
    if (oh < 18 && ow < 18) {
#pragma unroll
        for (int m = 0; m < 4; ++m) {
            int od = od0 + m;
            if (od < 18) {
                int pos = ((ot * 18 + od) * 18 + oh) * 18 + ow;
                ushort4 st;
                st.x = f2bf(fmaxf(acc[m][0], 0.f));
                st.y = f2bf(fmaxf(acc[m][1], 0.f));
                st.z = f2bf(fmaxf(acc[m][2], 0.f));
                st.w = f2bf(fmaxf(acc[m][3], 0.f));
                *(ushort4*)(out + (size_t)pos * 64 + wv * 16 + g * 4) = st;
            }
        }
    }
}

// ---------------- maxpool 3^4 s2 p1: bf16 [18^4][64] -> bf16 [9^4][64] ----------------
__global__ void maxpool2(const ushortT* __restrict__ in, ushortT* __restrict__ out,
                         ushortT* __restrict__ zb) {
    int idx = blockIdx.x * 256 + threadIdx.x;
    if (idx < 128) zb[idx] = 0;
    if (idx >= 6561 * 16) return;
    int c4 = idx & 15;
    int p = idx >> 4;
    int ow = p % 9; int t = p / 9;
    int oh = t % 9; t /= 9;
    int od = t % 9; int ot = t / 9;
    ushort4 m = {0, 0, 0, 0};
    for (int kt = 0; kt < 3; ++kt) { int it = 2 * ot + kt - 1; if ((unsigned)it >= 18u) continue;
        for (int kd = 0; kd < 3; ++kd) { int id = 2 * od + kd - 1; if ((unsigned)id >= 18u) continue;
            for (int kh = 0; kh < 3; ++kh) { int ih = 2 * oh + kh - 1; if ((unsigned)ih >= 18u) continue;
                int rb = ((it * 18 + id) * 18 + ih) * 18;
                for (int kw = 0; kw < 3; ++kw) { int iw = 2 * ow + kw - 1; if ((unsigned)iw >= 18u) continue;
                    ushort4 v = *(const ushort4*)(in + (size_t)(rb + iw) * 64 + c4 * 4);
                    m.x = v.x > m.x ? v.x : m.x;
                    m.y = v.y > m.y ? v.y : m.y;
                    m.z = v.z > m.z ? v.z : m.z;
                    m.w = v.w > m.w ? v.w : m.w;
                }
            }
        }
    }
    *(ushort4*)(out + (size_t)p * 64 + c4 * 4) = m;
}

// ---------------- MFMA implicit-GEMM residual conv (+ optional merged 1x1 downsample) ------
template <int KC, int FUSE>
__global__ void convmfma(const ushortT* __restrict__ xb, const ushortT* __restrict__ wt,
                         const float* __restrict__ bias, const ushortT* __restrict__ res,
                         ushortT* __restrict__ outb, float* __restrict__ part,
                         const ushortT* __restrict__ zq,
                         int Ci, int Co, int T, int O, int stride, int chunk,
                         const float* __restrict__ dwW, ushortT* __restrict__ dwOut) {
    if (dwW && blockIdx.y == (unsigned)(Co >> 6)) {
        int O2 = O * O, O3 = O2 * O, O4 = O3 * O;
        int total = Co * O4;
        int sthr = gridDim.x * gridDim.z * 256;
        for (int idx = (blockIdx.z * gridDim.x + blockIdx.x) * 256 + threadIdx.x;
             idx < total; idx += sthr) {
            int co = idx % Co;
            int pos = idx / Co;
            int ow = pos % O, oh = (pos / O) % O, od = (pos / O2) % O, ot = pos / O3;
            int ip = (((2 * ot) * T + 2 * od) * T + 2 * oh) * T + 2 * ow;
            const ushortT* xp = xb + (size_t)ip * Ci;
            const float* wp = dwW + (size_t)co * Ci;
            float acc = 0.f;
            for (int c8 = 0; c8 < Ci; c8 += 8) {
                uint4 xv = *(const uint4*)(xp + c8);
                float4 w0 = *(const float4*)(wp + c8);
                float4 w1 = *(const float4*)(wp + c8 + 4);
                acc = fmaf(bf2f((unsigned short)(xv.x & 0xffff)), w0.x, acc);
                acc = fmaf(bf2f((unsigned short)(xv.x >> 16)),    w0.y, acc);
                acc = fmaf(bf2f((unsigned short)(xv.y & 0xffff)), w0.z, acc);
                acc = fmaf(bf2f((unsigned short)(xv.y >> 16)),    w0.w, acc);
                acc = fmaf(bf2f((unsigned short)(xv.z & 0xffff)), w1.x, acc);
                acc = fmaf(bf2f((unsigned short)(xv.z >> 16)),    w1.y, acc);
                acc = fmaf(bf2f((unsigned short)(xv.w & 0xffff)), w1.z, acc);
                acc = fmaf(bf2f((unsigned short)(xv.w >> 16)),    w1.w, acc);
            }
            dwOut[idx] = f2bf(acc);
        }
        return;
    }

    int lane = threadIdx.x & 63;
    int wv = threadIdx.x >> 6;
    int p0 = blockIdx.x * 16;
    int co0 = (blockIdx.y * 4 + wv) * 16;
    int cbase = blockIdx.z * chunk;

    int pn = p0 + (lane & 15);
    int O2 = O * O, O3 = O2 * O, O4 = O3 * O;
    bool pv = pn < O4;
    int pc = pv ? pn : 0;
    int ow = pc % O, oh = (pc / O) % O, od = (pc / O2) % O, ot = pc / O3;
    int g = lane >> 4;
    int kl = cbase + g * 8;

    const ushortT* aRow = wt + (size_t)(co0 + (lane & 15)) * Ci + kl;
    size_t tapStride = (size_t)Co * Ci;
    const ushortT* zp = zq + g * 8;

    f32x4 acc = {0.f, 0.f, 0.f, 0.f};

    int itb = ot * stride - 1, idb = od * stride - 1, ihb = oh * stride - 1, iwb = ow * stride - 1;

    for (int i = 0; i < 3; ++i) {
        int it = itb + i;
        bool vt = pv && ((unsigned)it < (unsigned)T);
        for (int kd = 0; kd < 3; ++kd) {
            int id = idb + kd;
            bool vdd = vt && ((unsigned)id < (unsigned)T);
            int btd = (it * T + id) * T;
            for (int kh = 0; kh < 3; ++kh) {
                int ih = ihb + kh;
                bool vh = vdd && ((unsigned)ih < (unsigned)T);
                for (int kw = 0; kw < 3; ++kw) {
                    int iw = iwb + kw;
                    bool v = vh && ((unsigned)iw < (unsigned)T);
                    int ip = (btd + ih) * T + iw;
                    const ushortT* bp = v ? (xb + (size_t)ip * Ci + kl) : zp;
                    int tapIdx = (i * 9 + kd * 3 + kh) * 3 + kw;
                    const ushortT* apw = aRow + (size_t)tapIdx * tapStride;
#pragma unroll
                    for (int kc = 0; kc < KC; ++kc) {
                        bf16x8 av = *(const bf16x8*)(apw + kc * 32);
                        bf16x8 bv = *(const bf16x8*)(bp + kc * 32);
                        acc = __builtin_amdgcn_mfma_f32_16x16x32_bf16(av, bv, acc, 0, 0, 0);
                    }
                }
            }
        }
    }

    if (!pv) return;
    int cob = co0 + g * 4;
    if (FUSE) {
        float bb[4] = {0.f, 0.f, 0.f, 0.f};
        for (int i = 0; i < 3; ++i) {
            int it = itb + i;
            if ((unsigned)it < (unsigned)T) {
#pragma unroll
                for (int r = 0; r < 4; ++r) bb[r] += bias[i * Co + cob + r];
            }
        }
        float rv[4] = {0.f, 0.f, 0.f, 0.f};
        if (res) {
            ushort4 rr = *(const ushort4*)(res + (size_t)pn * Co + cob);
            rv[0] = bf2f(rr.x); rv[1] = bf2f(rr.y); rv[2] = bf2f(rr.z); rv[3] = bf2f(rr.w);
        }
        ushort4 st;
        st.x = f2bf(fmaxf(acc[0] + bb[0] + rv[0], 0.f));
        st.y = f2bf(fmaxf(acc[1] + bb[1] + rv[1], 0.f));
        st.z = f2bf(fmaxf(acc[2] + bb[2] + rv[2], 0.f));
        st.w = f2bf(fmaxf(acc[3] + bb[3] + rv[3], 0.f));
        *(ushort4*)(outb + (size_t)pn * Co + cob) = st;
    } else {
        *(f32x4*)(part + ((size_t)blockIdx.z * O4 + pn) * Co + cob) = acc;
    }
}

// ---------------- finalize for k-split convs ----------------
__global__ void finalize_k(const float* __restrict__ part, int KS,
                           const float* __restrict__ bias, const ushortT* __restrict__ res,
                           ushortT* __restrict__ outb, int Co, int O4, int T, int O, int stride,
                           int total) {
    int idx = blockIdx.x * 256 + threadIdx.x;
    if (idx >= total) return;
    int co = idx % Co;
    int pos = idx / Co;
    float v = 0.f;
    for (int z = 0; z < KS; ++z) v += part[((size_t)z * O4 + pos) * Co + co];
    int ot = pos / (O * O * O);
    for (int i = 0; i < 3; ++i) {
        int it = ot * stride + i - 1;
        if ((unsigned)it < (unsigned)T) v += bias[i * Co + co];
    }
    if (res) v += bf2f(res[idx]);
    outb[idx] = f2bf(fmaxf(v, 0.f));
}

// ---------------- avgpool 2^4 + FC (512 -> 1) ----------------
__global__ void avgfc2(const ushortT* __restrict__ xin, const float* __restrict__ fw,
                       const float* __restrict__ fb, float* __restrict__ out) {
    __shared__ float ls[8];
    int t = threadIdx.x; // 512
    float s = 0.f;
#pragma unroll
    for (int pp = 0; pp < 16; ++pp) s += bf2f(xin[pp * 512 + t]);
    s = s * (1.f / 16.f) * fw[t];
    for (int off = 32; off > 0; off >>= 1) s += __shfl_xor(s, off, 64);
    if ((t & 63) == 0) ls[t >> 6] = s;
    __syncthreads();
    if (t == 0) {
        float tot = 0.f;
#pragma unroll
        for (int i = 0; i < 8; ++i) tot += ls[i];
        out[0] = tot + fb[0];
    }
}

extern "C" void kernel_launch(void* const* d_in, const int* in_sizes, int n_in,
                              void* d_out, int out_size, void* d_ws, size_t ws_size,
                              hipStream_t stream) {
    const float* x       = (const float*)d_in[0];
    const float* conv1_w = (const float*)d_in[1];
    const float* l1_w1 = (const float*)d_in[2];
    const float* l1_b1 = (const float*)d_in[3];
    const float* l1_w2 = (const float*)d_in[4];
    const float* l1_b2 = (const float*)d_in[5];
    const float* l2_w1 = (const float*)d_in[6];
    const float* l2_b1 = (const float*)d_in[7];
    const float* l2_w2 = (const float*)d_in[8];
    const float* l2_b2 = (const float*)d_in[9];
    const float* l2_dw = (const float*)d_in[10];
    const float* l3_w1 = (const float*)d_in[11];
    const float* l3_b1 = (const float*)d_in[12];
    const float* l3_w2 = (const float*)d_in[13];
    const float* l3_b2 = (const float*)d_in[14];
    const float* l3_dw = (const float*)d_in[15];
    const float* l4_w1 = (const float*)d_in[16];
    const float* l4_b1 = (const float*)d_in[17];
    const float* l4_w2 = (const float*)d_in[18];
    const float* l4_b2 = (const float*)d_in[19];
    const float* l4_dw = (const float*)d_in[20];
    const float* fc_w  = (const float*)d_in[21];
    const float* fc_b  = (const float*)d_in[22];
    float* outp = (float*)d_out;

    char* bp = (char*)d_ws;
    auto alloc = [&](size_t bytes) {
        char* r = bp;
        bp += (bytes + 255) & ~(size_t)255;
        return (void*)r;
    };
    ushortT* A16 = (ushortT*)alloc(6718464ull * 2); // conv1 out bf16 [18^4][64]
    ushortT* Aw1 = (ushortT*)alloc(200704ull * 2);
    ushortT* X0 = (ushortT*)alloc(419904ull * 2);
    ushortT* Y1 = (ushortT*)alloc(419904ull * 2);
    ushortT* X1 = (ushortT*)alloc(419904ull * 2);
    ushortT* Y2 = (ushortT*)alloc(80000ull * 2);
    ushortT* R2 = (ushortT*)alloc(80000ull * 2);
    ushortT* X2 = (ushortT*)alloc(80000ull * 2);
    ushortT* Y3 = (ushortT*)alloc(20736ull * 2);
    ushortT* R3 = (ushortT*)alloc(20736ull * 2);
    ushortT* X3 = (ushortT*)alloc(20736ull * 2);
    ushortT* Y4 = (ushortT*)alloc(8192ull * 2);
    ushortT* R4 = (ushortT*)alloc(8192ull * 2);
    ushortT* X4 = (ushortT*)alloc(8192ull * 2);
    ushortT* W11 = (ushortT*)alloc(331776ull * 2);
    ushortT* W12 = (ushortT*)alloc(331776ull * 2);
    ushortT* W21 = (ushortT*)alloc(663552ull * 2);
    ushortT* W22 = (ushortT*)alloc(1327104ull * 2);
    ushortT* W31 = (ushortT*)alloc(2654208ull * 2);
    ushortT* W32 = (ushortT*)alloc(5308416ull * 2);
    ushortT* W41 = (ushortT*)alloc(10616832ull * 2);
    ushortT* W42 = (ushortT*)alloc(21233664ull * 2);
    float* P    = (float*)alloc(165888ull * 4);
    ushortT* ZB = (ushortT*)alloc(256);
    if ((size_t)(bp - (char*)d_ws) > ws_size) return; // workspace too small: fail cleanly

    // ---- all weight prep in one launch (both-sides coalesced) ----
    wprep_combined<<<6544, 256, 0, stream>>>(conv1_w, l1_w1, l1_w2, l2_w1, l2_w2, l3_w1,
                                             l3_w2, l4_w1, l4_w2,
                                             Aw1, W11, W12, W21, W22, W31, W32, W41, W42, ZB);

    // ---- stem ----
    conv1_mfma4<<<2250, 256, 0, stream>>>(x, Aw1, A16);
    maxpool2<<<411, 256, 0, stream>>>(A16, X0, ZB);

    // ---- layer1: 64->64, T=9, s1, identity residual ----
    convmfma<2, 1><<<dim3(411, 1, 1), 256, 0, stream>>>(X0, W11, l1_b1, nullptr, Y1, nullptr,
                                                        ZB, 64, 64, 9, 9, 1, 64,
                                                        nullptr, nullptr);
    convmfma<2, 1><<<dim3(411, 1, 1), 256, 0, stream>>>(Y1, W12, l1_b2, X0, X1, nullptr,
                                                        ZB, 64, 64, 9, 9, 1, 64,
                                                        nullptr, nullptr);

    // ---- layer2: 64->128, 9->5, s2 (dw merged into c1 launch) ----
    convmfma<2, 1><<<dim3(40, 3, 1), 256, 0, stream>>>(X1, W21, l2_b1, nullptr, Y2, nullptr,
                                                       ZB, 64, 128, 9, 5, 2, 64,
                                                       l2_dw, R2);
    convmfma<4, 1><<<dim3(40, 2, 1), 256, 0, stream>>>(Y2, W22, l2_b2, R2, X2, nullptr,
                                                       ZB, 128, 128, 5, 5, 1, 128,
                                                       nullptr, nullptr);

    // ---- layer3: 128->256, 5->3, s2 (c1 KS=4 + merged dw; c2 KS=8) ----
    convmfma<1, 0><<<dim3(6, 5, 4), 256, 0, stream>>>(X2, W31, nullptr, nullptr, nullptr, P,
                                                      ZB, 128, 256, 5, 3, 2, 32,
                                                      l3_dw, R3);
    finalize_k<<<81, 256, 0, stream>>>(P, 4, l3_b1, nullptr, Y3, 256, 81, 5, 3, 2, 20736);
    convmfma<1, 0><<<dim3(6, 4, 8), 256, 0, stream>>>(Y3, W32, nullptr, nullptr, nullptr, P,
                                                      ZB, 256, 256, 3, 3, 1, 32,
                                                      nullptr, nullptr);
    finalize_k<<<81, 256, 0, stream>>>(P, 8, l3_b2, R3, X3, 256, 81, 3, 3, 1, 20736);

    // ---- layer4: 256->512, 3->2, s2 (c1 KS=8 + merged dw; c2 KS=16) ----
    convmfma<1, 0><<<dim3(1, 9, 8), 256, 0, stream>>>(X3, W41, nullptr, nullptr, nullptr, P,
                                                      ZB, 256, 512, 3, 2, 2, 32,
                                                      l4_dw, R4);
    finalize_k<<<32, 256, 0, stream>>>(P, 8, l4_b1, nullptr, Y4, 512, 16, 3, 2, 2, 8192);
    convmfma<1, 0><<<dim3(1, 8, 16), 256, 0, stream>>>(Y4, W42, nullptr, nullptr, nullptr, P,
                                                       ZB, 512, 512, 2, 2, 1, 32,
                                                       nullptr, nullptr);
    finalize_k<<<32, 256, 0, stream>>>(P, 16, l4_b2, R4, X4, 512, 16, 2, 2, 1, 8192);

    // ---- head ----
    avgfc2<<<1, 512, 0, stream>>>(X4, fc_w, fc_b, outp);
}

// Round 8
// 547.224 us; speedup vs baseline: 1.7683x; 1.1579x over previous
//
#include <hip/hip_runtime.h>

typedef __bf16 bf16x8 __attribute__((ext_vector_type(8)));
typedef float f32x4 __attribute__((ext_vector_type(4)));
typedef unsigned short ushortT;

__device__ __forceinline__ unsigned short f2bf(float f) {
    unsigned u = __float_as_uint(f);
    u += 0x7fffu + ((u >> 16) & 1u);
    return (unsigned short)(u >> 16);
}
__device__ __forceinline__ float bf2f(unsigned short h) {
    return __uint_as_float((unsigned)h << 16);
}

// ---------------- prep0: pad+convert x to bf16 [42][42][42][48]; repack conv1 weights ------
// xpad: blocks [0,1737): ushort8 per thread over 42*42*42*6 chunks.
// conv1 w: blocks [1737,2521): (7,64,1,7,7,7) f32 -> bf16 [co][3136], k=(kt*7+kd)*64+kh*8+kw.
__global__ __launch_bounds__(256) void prep0(const float* __restrict__ x,
                                             const float* __restrict__ c1w,
                                             ushortT* __restrict__ xp,
                                             ushortT* __restrict__ o1) {
    int bid = blockIdx.x, tid = threadIdx.x;
    if (bid < 1737) {
        long idx = (long)bid * 256 + tid;
        if (idx >= 444528L) return;
        int q = (int)(idx % 6); long r = idx / 6;
        int h = (int)(r % 42); r /= 42;
        int d = (int)(r % 42); int t = (int)(r / 42);
        int tt = t - 3, dd = d - 3, hh = h - 3;
        bool rok = ((unsigned)tt < 36u) && ((unsigned)dd < 36u) && ((unsigned)hh < 36u);
        const float* src = x + (((long)tt * 36 + dd) * 36 + hh) * 36;
        union { ushortT s[8]; uint4 u; } v;
#pragma unroll
        for (int j = 0; j < 8; ++j) {
            int ww = q * 8 + j - 3;
            float f = (rok && (unsigned)ww < 36u) ? src[ww] : 0.f;
            v.s[j] = f2bf(f);
        }
        *(uint4*)(xp + idx * 8) = v.u;
    } else {
        int e = (bid - 1737) * 256 + tid; // 784*256 = 200704 exact
        if (e < 200704) {
            int k = e % 3136, co = e / 3136;
            int kw = k & 7, kh = (k >> 3) & 7, kdt = k >> 6;
            int kt = kdt / 7, kd = kdt % 7;
            float v = 0.f;
            if (kh < 7 && kw < 7)
                v = c1w[(size_t)(kt * 64 + co) * 343 + kd * 49 + kh * 7 + kw];
            o1[e] = f2bf(v);
        }
    }
}

// ---------------- mega: conv1 MFMA (blocks [0,1350)) + residual-weight prep (rest) ---------
// conv1: block=128thr (2 waves), out tile = 96 pos (1ot x 6od x 4oh x 4ow) x 64 co.
//   Wave: 32 co (c=2 subtiles) x 96 pos (m=6). Per K=32 step: 2 A-glob loads, 6 B LDS reads,
//   12 MFMA -> B-feed 8B/MFMA (LDS no longer the bound). kt-sliced double-buffered LDS
//   (2 x [17][14][20] ushorts = 19KB). Row stride 20 ush = 10 dwords -> <=2-way banks.
// wprep: per block one (tensor, i, co, ci64) tile: f32 [64ci][27] -> bf16 [tap][64ci],
//   both sides coalesced via LDS.
__global__ __launch_bounds__(128) void mega_kernel(
        const ushortT* __restrict__ xp, const ushortT* __restrict__ aw,
        ushortT* __restrict__ outc1,
        const float* __restrict__ w11, const float* __restrict__ w12,
        const float* __restrict__ w21, const float* __restrict__ w22,
        const float* __restrict__ w31, const float* __restrict__ w32,
        const float* __restrict__ w41, const float* __restrict__ w42,
        ushortT* __restrict__ o11, ushortT* __restrict__ o12,
        ushortT* __restrict__ o21, ushortT* __restrict__ o22,
        ushortT* __restrict__ o31, ushortT* __restrict__ o32,
        ushortT* __restrict__ o41, ushortT* __restrict__ o42) {
    __shared__ __align__(16) ushortT smem[9520];
    int bid = blockIdx.x, tid = threadIdx.x;

    if (bid < 1350) {
        int wt = bid % 5; int r = bid / 5;
        int ht = r % 5; r /= 5;
        int dt = r % 3; int ot = r / 3;
        int ow0 = wt * 4, oh0 = ht * 4, od0 = dt * 6;
        int gw0 = 2 * ow0, gh0 = 2 * oh0, gd0 = 2 * od0;

        int lane = tid & 63, wv = tid >> 6;
        int l15 = lane & 15, g = lane >> 4;
        int dh = l15 >> 2, dw = l15 & 3;

        const ushortT* ap0 = aw + (size_t)(wv * 32 + l15) * 3136 + g * 8;
        const ushortT* ap1 = ap0 + 16 * 3136;

        ushortT* curb = smem;
        ushortT* nxtb = smem + 4760;

        auto stage = [&](ushortT* buf, int kt) {
            int gt = 2 * ot + kt;
            for (int rr = tid; rr < 238; rr += 128) {
                int ld = rr / 14, lh = rr - ld * 14;
                const ushortT* s = xp +
                    ((size_t)((gt * 42 + gd0 + ld) * 42 + gh0 + lh)) * 48 + gw0;
                uint4 a = *(const uint4*)s;
                uint4 b = *(const uint4*)(s + 8);
                ushortT* d = buf + rr * 20;
                *(uint2*)(d)      = make_uint2(a.x, a.y);
                *(uint2*)(d + 4)  = make_uint2(a.z, a.w);
                *(uint2*)(d + 8)  = make_uint2(b.x, b.y);
                *(uint2*)(d + 12) = make_uint2(b.z, b.w);
            }
        };

        f32x4 acc[2][6];
#pragma unroll
        for (int c = 0; c < 2; ++c)
#pragma unroll
            for (int m = 0; m < 6; ++m) acc[c][m] = (f32x4){0.f, 0.f, 0.f, 0.f};

        stage(curb, 0);
        __syncthreads();

        int lhl = (2 * dh + g) * 20 + 2 * dw; // + khq*80 added in loop
        int kidx = 0;
        for (int kt = 0; kt < 7; ++kt) {
            if (kt < 6) stage(nxtb, kt + 1);
            for (int kd = 0; kd < 7; ++kd) {
                int C0 = kd * 280 + lhl;
#pragma unroll
                for (int khq = 0; khq < 2; ++khq) {
                    bf16x8 a0 = *(const bf16x8*)(ap0 + kidx);
                    bf16x8 a1 = *(const bf16x8*)(ap1 + kidx);
                    kidx += 32;
                    int C = C0 + khq * 80;
#pragma unroll
                    for (int m = 0; m < 6; ++m) {
                        int off = C + m * 560;
                        union { unsigned u[4]; bf16x8 v; } bb;
                        bb.u[0] = *(const unsigned*)(curb + off);
                        bb.u[1] = *(const unsigned*)(curb + off + 2);
                        bb.u[2] = *(const unsigned*)(curb + off + 4);
                        bb.u[3] = *(const unsigned*)(curb + off + 6);
                        acc[0][m] = __builtin_amdgcn_mfma_f32_16x16x32_bf16(a0, bb.v, acc[0][m], 0, 0, 0);
                        acc[1][m] = __builtin_amdgcn_mfma_f32_16x16x32_bf16(a1, bb.v, acc[1][m], 0, 0, 0);
                    }
                }
            }
            __syncthreads();
            ushortT* t2 = curb; curb = nxtb; nxtb = t2;
        }

        int oh = oh0 + dh, ow = ow0 + dw;
        if (oh < 18 && ow < 18) {
#pragma unroll
            for (int m = 0; m < 6; ++m) {
                int od = od0 + m; // always < 18 (od0 <= 12)
                int pos = ((ot * 18 + od) * 18 + oh) * 18 + ow;
#pragma unroll
                for (int c = 0; c < 2; ++c) {
                    ushort4 st;
                    st.x = f2bf(fmaxf(acc[c][m][0], 0.f));
                    st.y = f2bf(fmaxf(acc[c][m][1], 0.f));
                    st.z = f2bf(fmaxf(acc[c][m][2], 0.f));
                    st.w = f2bf(fmaxf(acc[c][m][3], 0.f));
                    *(ushort4*)(outc1 + (size_t)pos * 64 + wv * 32 + c * 16 + g * 4) = st;
                }
            }
        }
        return;
    }

    // ---- residual weight prep tiles ----
    int wb = bid - 1350;
    const float* in; ushortT* out; int Ci, Co, nc, base;
    if (wb < 1536) {
        if (wb < 384) {
            if (wb < 192) { in = w11; out = o11; Ci = 64; Co = 64; nc = 1; base = 0; }
            else          { in = w12; out = o12; Ci = 64; Co = 64; nc = 1; base = 192; }
        } else if (wb < 768) { in = w21; out = o21; Ci = 64;  Co = 128; nc = 1; base = 384; }
        else                 { in = w22; out = o22; Ci = 128; Co = 128; nc = 2; base = 768; }
    } else if (wb < 6144) {
        if (wb < 3072) { in = w31; out = o31; Ci = 128; Co = 256; nc = 2; base = 1536; }
        else           { in = w32; out = o32; Ci = 256; Co = 256; nc = 4; base = 3072; }
    } else {
        if (wb < 12288) { in = w41; out = o41; Ci = 256; Co = 512; nc = 4; base = 6144; }
        else            { in = w42; out = o42; Ci = 512; Co = 512; nc = 8; base = 12288; }
    }
    int lb = wb - base;
    int c64 = lb % nc;
    int co = (lb / nc) % Co;
    int i = lb / (nc * Co);

    const float* src = in + ((size_t)(i * Co + co) * Ci + 64 * c64) * 27;
    float* tile = (float*)smem; // 1728 floats = 6912B
    for (int e = tid; e < 432; e += 128)
        *(float4*)(tile + 4 * e) = *(const float4*)(src + 4 * e);
    __syncthreads();
    ushortT* dst = out + (size_t)(i * 27) * Co * Ci + (size_t)co * Ci + 64 * c64;
    size_t tapstride = (size_t)Co * Ci;
    for (int e = tid; e < 432; e += 128) {
        int tap = e >> 4, q = e & 15;
        ushort4 v;
        v.x = f2bf(tile[(4 * q + 0) * 27 + tap]);
        v.y = f2bf(tile[(4 * q + 1) * 27 + tap]);
        v.z = f2bf(tile[(4 * q + 2) * 27 + tap]);
        v.w = f2bf(tile[(4 * q + 3) * 27 + tap]);
        *(ushort4*)(dst + (size_t)tap * tapstride + 4 * q) = v;
    }
}

// ---------------- maxpool 3^4 s2 p1: bf16 [18^4][64] -> bf16 [9^4][64]; zero-fills zb ------
__global__ void maxpool2(const ushortT* __restrict__ in, ushortT* __restrict__ out,
                         ushortT* __restrict__ zb) {
    int idx = blockIdx.x * 256 + threadIdx.x;
    if (idx < 128) zb[idx] = 0;
    if (idx >= 6561 * 16) return;
    int c4 = idx & 15;
    int p = idx >> 4;
    int ow = p % 9; int t = p / 9;
    int oh = t % 9; t /= 9;
    int od = t % 9; int ot = t / 9;
    ushort4 m = {0, 0, 0, 0};
    for (int kt = 0; kt < 3; ++kt) { int it = 2 * ot + kt - 1; if ((unsigned)it >= 18u) continue;
        for (int kd = 0; kd < 3; ++kd) { int id = 2 * od + kd - 1; if ((unsigned)id >= 18u) continue;
            for (int kh = 0; kh < 3; ++kh) { int ih = 2 * oh + kh - 1; if ((unsigned)ih >= 18u) continue;
                int rb = ((it * 18 + id) * 18 + ih) * 18;
                for (int kw = 0; kw < 3; ++kw) { int iw = 2 * ow + kw - 1; if ((unsigned)iw >= 18u) continue;
                    ushort4 v = *(const ushort4*)(in + (size_t)(rb + iw) * 64 + c4 * 4);
                    m.x = v.x > m.x ? v.x : m.x;
                    m.y = v.y > m.y ? v.y : m.y;
                    m.z = v.z > m.z ? v.z : m.z;
                    m.w = v.w > m.w ? v.w : m.w;
                }
            }
        }
    }
    *(ushort4*)(out + (size_t)p * 64 + c4 * 4) = m;
}

// ---------------- MFMA implicit-GEMM residual conv (+ optional merged 1x1 downsample) ------
template <int KC, int FUSE>
__global__ void convmfma(const ushortT* __restrict__ xb, const ushortT* __restrict__ wt,
                         const float* __restrict__ bias, const ushortT* __restrict__ res,
                         ushortT* __restrict__ outb, float* __restrict__ part,
                         const ushortT* __restrict__ zq,
                         int Ci, int Co, int T, int O, int stride, int chunk,
                         const float* __restrict__ dwW, ushortT* __restrict__ dwOut) {
    if (dwW && blockIdx.y == (unsigned)(Co >> 6)) {
        int O2 = O * O, O3 = O2 * O, O4 = O3 * O;
        int total = Co * O4;
        int sthr = gridDim.x * gridDim.z * 256;
        for (int idx = (blockIdx.z * gridDim.x + blockIdx.x) * 256 + threadIdx.x;
             idx < total; idx += sthr) {
            int co = idx % Co;
            int pos = idx / Co;
            int ow = pos % O, oh = (pos / O) % O, od = (pos / O2) % O, ot = pos / O3;
            int ip = (((2 * ot) * T + 2 * od) * T + 2 * oh) * T + 2 * ow;
            const ushortT* xpp = xb + (size_t)ip * Ci;
            const float* wp = dwW + (size_t)co * Ci;
            float acc = 0.f;
            for (int c8 = 0; c8 < Ci; c8 += 8) {
                uint4 xv = *(const uint4*)(xpp + c8);
                float4 w0 = *(const float4*)(wp + c8);
                float4 w1 = *(const float4*)(wp + c8 + 4);
                acc = fmaf(bf2f((unsigned short)(xv.x & 0xffff)), w0.x, acc);
                acc = fmaf(bf2f((unsigned short)(xv.x >> 16)),    w0.y, acc);
                acc = fmaf(bf2f((unsigned short)(xv.y & 0xffff)), w0.z, acc);
                acc = fmaf(bf2f((unsigned short)(xv.y >> 16)),    w0.w, acc);
                acc = fmaf(bf2f((unsigned short)(xv.z & 0xffff)), w1.x, acc);
                acc = fmaf(bf2f((unsigned short)(xv.z >> 16)),    w1.y, acc);
                acc = fmaf(bf2f((unsigned short)(xv.w & 0xffff)), w1.z, acc);
                acc = fmaf(bf2f((unsigned short)(xv.w >> 16)),    w1.w, acc);
            }
            dwOut[idx] = f2bf(acc);
        }
        return;
    }

    int lane = threadIdx.x & 63;
    int wv = threadIdx.x >> 6;
    int p0 = blockIdx.x * 16;
    int co0 = (blockIdx.y * 4 + wv) * 16;
    int cbase = blockIdx.z * chunk;

    int pn = p0 + (lane & 15);
    int O2 = O * O, O3 = O2 * O, O4 = O3 * O;
    bool pv = pn < O4;
    int pc = pv ? pn : 0;
    int ow = pc % O, oh = (pc / O) % O, od = (pc / O2) % O, ot = pc / O3;
    int g = lane >> 4;
    int kl = cbase + g * 8;

    const ushortT* aRow = wt + (size_t)(co0 + (lane & 15)) * Ci + kl;
    size_t tapStride = (size_t)Co * Ci;
    const ushortT* zp = zq + g * 8;

    f32x4 acc = {0.f, 0.f, 0.f, 0.f};

    int itb = ot * stride - 1, idb = od * stride - 1, ihb = oh * stride - 1, iwb = ow * stride - 1;

    for (int i = 0; i < 3; ++i) {
        int it = itb + i;
        bool vt = pv && ((unsigned)it < (unsigned)T);
        for (int kd = 0; kd < 3; ++kd) {
            int id = idb + kd;
            bool vdd = vt && ((unsigned)id < (unsigned)T);
            int btd = (it * T + id) * T;
            for (int kh = 0; kh < 3; ++kh) {
                int ih = ihb + kh;
                bool vh = vdd && ((unsigned)ih < (unsigned)T);
                for (int kw = 0; kw < 3; ++kw) {
                    int iw = iwb + kw;
                    bool v = vh && ((unsigned)iw < (unsigned)T);
                    int ip = (btd + ih) * T + iw;
                    const ushortT* bp = v ? (xb + (size_t)ip * Ci + kl) : zp;
                    int tapIdx = (i * 9 + kd * 3 + kh) * 3 + kw;
                    const ushortT* apw = aRow + (size_t)tapIdx * tapStride;
#pragma unroll
                    for (int kc = 0; kc < KC; ++kc) {
                        bf16x8 av = *(const bf16x8*)(apw + kc * 32);
                        bf16x8 bv = *(const bf16x8*)(bp + kc * 32);
                        acc = __builtin_amdgcn_mfma_f32_16x16x32_bf16(av, bv, acc, 0, 0, 0);
                    }
                }
            }
        }
    }

    if (!pv) return;
    int cob = co0 + g * 4;
    if (FUSE) {
        float bb[4] = {0.f, 0.f, 0.f, 0.f};
        for (int i = 0; i < 3; ++i) {
            int it = itb + i;
            if ((unsigned)it < (unsigned)T) {
#pragma unroll
                for (int r = 0; r < 4; ++r) bb[r] += bias[i * Co + cob + r];
            }
        }
        float rv[4] = {0.f, 0.f, 0.f, 0.f};
        if (res) {
            ushort4 rr = *(const ushort4*)(res + (size_t)pn * Co + cob);
            rv[0] = bf2f(rr.x); rv[1] = bf2f(rr.y); rv[2] = bf2f(rr.z); rv[3] = bf2f(rr.w);
        }
        ushort4 st;
        st.x = f2bf(fmaxf(acc[0] + bb[0] + rv[0], 0.f));
        st.y = f2bf(fmaxf(acc[1] + bb[1] + rv[1], 0.f));
        st.z = f2bf(fmaxf(acc[2] + bb[2] + rv[2], 0.f));
        st.w = f2bf(fmaxf(acc[3] + bb[3] + rv[3], 0.f));
        *(ushort4*)(outb + (size_t)pn * Co + cob) = st;
    } else {
        *(f32x4*)(part + ((size_t)blockIdx.z * O4 + pn) * Co + cob) = acc;
    }
}

// ---------------- finalize for k-split convs ----------------
__global__ void finalize_k(const float* __restrict__ part, int KS,
                           const float* __restrict__ bias, const ushortT* __restrict__ res,
                           ushortT* __restrict__ outb, int Co, int O4, int T, int O, int stride,
                           int total) {
    int idx = blockIdx.x * 256 + threadIdx.x;
    if (idx >= total) return;
    int co = idx % Co;
    int pos = idx / Co;
    float v = 0.f;
    for (int z = 0; z < KS; ++z) v += part[((size_t)z * O4 + pos) * Co + co];
    int ot = pos / (O * O * O);
    for (int i = 0; i < 3; ++i) {
        int it = ot * stride + i - 1;
        if ((unsigned)it < (unsigned)T) v += bias[i * Co + co];
    }
    if (res) v += bf2f(res[idx]);
    outb[idx] = f2bf(fmaxf(v, 0.f));
}

// ---------------- avgpool 2^4 + FC (512 -> 1) ----------------
__global__ void avgfc2(const ushortT* __restrict__ xin, const float* __restrict__ fw,
                       const float* __restrict__ fb, float* __restrict__ out) {
    __shared__ float ls[8];
    int t = threadIdx.x; // 512
    float s = 0.f;
#pragma unroll
    for (int pp = 0; pp < 16; ++pp) s += bf2f(xin[pp * 512 + t]);
    s = s * (1.f / 16.f) * fw[t];
    for (int off = 32; off > 0; off >>= 1) s += __shfl_xor(s, off, 64);
    if ((t & 63) == 0) ls[t >> 6] = s;
    __syncthreads();
    if (t == 0) {
        float tot = 0.f;
#pragma unroll
        for (int i = 0; i < 8; ++i) tot += ls[i];
        out[0] = tot + fb[0];
    }
}

extern "C" void kernel_launch(void* const* d_in, const int* in_sizes, int n_in,
                              void* d_out, int out_size, void* d_ws, size_t ws_size,
                              hipStream_t stream) {
    const float* x       = (const float*)d_in[0];
    const float* conv1_w = (const float*)d_in[1];
    const float* l1_w1 = (const float*)d_in[2];
    const float* l1_b1 = (const float*)d_in[3];
    const float* l1_w2 = (const float*)d_in[4];
    const float* l1_b2 = (const float*)d_in[5];
    const float* l2_w1 = (const float*)d_in[6];
    const float* l2_b1 = (const float*)d_in[7];
    const float* l2_w2 = (const float*)d_in[8];
    const float* l2_b2 = (const float*)d_in[9];
    const float* l2_dw = (const float*)d_in[10];
    const float* l3_w1 = (const float*)d_in[11];
    const float* l3_b1 = (const float*)d_in[12];
    const float* l3_w2 = (const float*)d_in[13];
    const float* l3_b2 = (const float*)d_in[14];
    const float* l3_dw = (const float*)d_in[15];
    const float* l4_w1 = (const float*)d_in[16];
    const float* l4_b1 = (const float*)d_in[17];
    const float* l4_w2 = (const float*)d_in[18];
    const float* l4_b2 = (const float*)d_in[19];
    const float* l4_dw = (const float*)d_in[20];
    const float* fc_w  = (const float*)d_in[21];
    const float* fc_b  = (const float*)d_in[22];
    float* outp = (float*)d_out;

    char* bp = (char*)d_ws;
    auto alloc = [&](size_t bytes) {
        char* r = bp;
        bp += (bytes + 255) & ~(size_t)255;
        return (void*)r;
    };
    ushortT* A16 = (ushortT*)alloc(6718464ull * 2); // conv1 out bf16 [18^4][64]
    ushortT* XP  = (ushortT*)alloc(3556224ull * 2); // padded bf16 x [42][42][42][48]
    ushortT* Aw1 = (ushortT*)alloc(200704ull * 2);
    ushortT* X0 = (ushortT*)alloc(419904ull * 2);
    ushortT* Y1 = (ushortT*)alloc(419904ull * 2);
    ushortT* X1 = (ushortT*)alloc(419904ull * 2);
    ushortT* Y2 = (ushortT*)alloc(80000ull * 2);
    ushortT* R2 = (ushortT*)alloc(80000ull * 2);
    ushortT* X2 = (ushortT*)alloc(80000ull * 2);
    ushortT* Y3 = (ushortT*)alloc(20736ull * 2);
    ushortT* R3 = (ushortT*)alloc(20736ull * 2);
    ushortT* X3 = (ushortT*)alloc(20736ull * 2);
    ushortT* Y4 = (ushortT*)alloc(8192ull * 2);
    ushortT* R4 = (ushortT*)alloc(8192ull * 2);
    ushortT* X4 = (ushortT*)alloc(8192ull * 2);
    ushortT* W11 = (ushortT*)alloc(331776ull * 2);
    ushortT* W12 = (ushortT*)alloc(331776ull * 2);
    ushortT* W21 = (ushortT*)alloc(663552ull * 2);
    ushortT* W22 = (ushortT*)alloc(1327104ull * 2);
    ushortT* W31 = (ushortT*)alloc(2654208ull * 2);
    ushortT* W32 = (ushortT*)alloc(5308416ull * 2);
    ushortT* W41 = (ushortT*)alloc(10616832ull * 2);
    ushortT* W42 = (ushortT*)alloc(21233664ull * 2);
    float* P    = (float*)alloc(165888ull * 4);
    ushortT* ZB = (ushortT*)alloc(256);
    if ((size_t)(bp - (char*)d_ws) > ws_size) return; // workspace too small: fail cleanly

    // ---- prep0: pad/convert x + repack conv1 weights ----
    prep0<<<2521, 256, 0, stream>>>(x, conv1_w, XP, Aw1);

    // ---- mega: conv1 MFMA + all residual weight prep in one launch ----
    mega_kernel<<<25926, 128, 0, stream>>>(XP, Aw1, A16,
                                           l1_w1, l1_w2, l2_w1, l2_w2, l3_w1, l3_w2,
                                           l4_w1, l4_w2,
                                           W11, W12, W21, W22, W31, W32, W41, W42);

    // ---- stem pool ----
    maxpool2<<<411, 256, 0, stream>>>(A16, X0, ZB);

    // ---- layer1: 64->64, T=9, s1, identity residual ----
    convmfma<2, 1><<<dim3(411, 1, 1), 256, 0, stream>>>(X0, W11, l1_b1, nullptr, Y1, nullptr,
                                                        ZB, 64, 64, 9, 9, 1, 64,
                                                        nullptr, nullptr);
    convmfma<2, 1><<<dim3(411, 1, 1), 256, 0, stream>>>(Y1, W12, l1_b2, X0, X1, nullptr,
                                                        ZB, 64, 64, 9, 9, 1, 64,
                                                        nullptr, nullptr);

    // ---- layer2: 64->128, 9->5, s2 (dw merged into c1 launch) ----
    convmfma<2, 1><<<dim3(40, 3, 1), 256, 0, stream>>>(X1, W21, l2_b1, nullptr, Y2, nullptr,
                                                       ZB, 64, 128, 9, 5, 2, 64,
                                                       l2_dw, R2);
    convmfma<4, 1><<<dim3(40, 2, 1), 256, 0, stream>>>(Y2, W22, l2_b2, R2, X2, nullptr,
                                                       ZB, 128, 128, 5, 5, 1, 128,
                                                       nullptr, nullptr);

    // ---- layer3: 128->256, 5->3, s2 (c1 KS=4 + merged dw; c2 KS=8) ----
    convmfma<1, 0><<<dim3(6, 5, 4), 256, 0, stream>>>(X2, W31, nullptr, nullptr, nullptr, P,
                                                      ZB, 128, 256, 5, 3, 2, 32,
                                                      l3_dw, R3);
    finalize_k<<<81, 256, 0, stream>>>(P, 4, l3_b1, nullptr, Y3, 256, 81, 5, 3, 2, 20736);
    convmfma<1, 0><<<dim3(6, 4, 8), 256, 0, stream>>>(Y3, W32, nullptr, nullptr, nullptr, P,
                                                      ZB, 256, 256, 3, 3, 1, 32,
                                                      nullptr, nullptr);
    finalize_k<<<81, 256, 0, stream>>>(P, 8, l3_b2, R3, X3, 256, 81, 3, 3, 1, 20736);

    // ---- layer4: 256->512, 3->2, s2 (c1 KS=8 + merged dw; c2 KS=16) ----
    convmfma<1, 0><<<dim3(1, 9, 8), 256, 0, stream>>>(X3, W41, nullptr, nullptr, nullptr, P,
                                                      ZB, 256, 512, 3, 2, 2, 32,
                                                      l4_dw, R4);
    finalize_k<<<32, 256, 0, stream>>>(P, 8, l4_b1, nullptr, Y4, 512, 16, 3, 2, 2, 8192);
    convmfma<1, 0><<<dim3(1, 8, 16), 256, 0, stream>>>(Y4, W42, nullptr, nullptr, nullptr, P,
                                                       ZB, 512, 512, 2, 2, 1, 32,
                                                       nullptr, nullptr);
    finalize_k<<<32, 256, 0, stream>>>(P, 16, l4_b2, R4, X4, 512, 16, 2, 2, 1, 8192);

    // ---- head ----
    avgfc2<<<1, 512, 0, stream>>>(X4, fc_w, fc_b, outp);
}